// Round 2
// baseline (2282.684 us; speedup 1.0000x reference)
//
#include <hip/hip_runtime.h>
#include <stdint.h>

#define K_SEL 512
#define NBOX 1536          // 3 * K_SEL
#define CAND_CAP 4096
#define NBINS 65536

// scale params
#define M0 32448           // 64*13*13*3
#define M1 129792          // 64*26*26*3
#define M2 519168          // 64*52*52*3
#define M_TOT (M0+M1+M2)   // 681408

// ws byte offsets (all 16-aligned)
#define OFF_HIST 0u           // 3*65536*4 = 786432
#define OFF_CNT  786432u      // 3*4
#define OFF_THR  786448u      // 3*4
#define OFF_CAND 786464u      // 3*4096*8 = 98304
#define OFF_TOPK 884768u      // 1536*8
#define OFF_BOX  897056u      // 1536*7*4
#define OFF_SKEY 940064u      // 1536*8
#define OFF_SBOX 952352u      // 1536*7*4
#define OFF_GEOM 995360u      // 5*1536*4

typedef unsigned long long u64;
typedef uint32_t u32;

__device__ __forceinline__ float sigf(float x) { return 1.0f / (1.0f + expf(-x)); }

__device__ __forceinline__ u32 fmono(float f) {
    u32 u = __float_as_uint(f);
    return (u & 0x80000000u) ? ~u : (u | 0x80000000u);
}

// map flat thread t over all scales -> (s, c, H)
__device__ __forceinline__ void scale_of(int t, int& s, int& c, int& H) {
    if (t < M0)            { s = 0; c = t;           H = 13; }
    else if (t < M0 + M1)  { s = 1; c = t - M0;      H = 26; }
    else                   { s = 2; c = t - M0 - M1; H = 52; }
}

__device__ __forceinline__ float conf_logit(const float* p, int c, int H) {
    int HW = H * H;
    int hw3 = HW * 3;
    int n = c / hw3; int rem = c - n * hw3;
    int pix = rem / 3; int a = rem - pix * 3;
    return p[(size_t)(n * 255 + a * 85) * HW + pix];
}

// ---------------- kernel 1: zero scratch ----------------
__global__ void k_zero(uint8_t* ws) {
    u32* hist = (u32*)(ws + OFF_HIST);
    int t = blockIdx.x * blockDim.x + threadIdx.x;
    if (t < 3 * NBINS) hist[t] = 0;
    if (t < 3) ((u32*)(ws + OFF_CNT))[t] = 0;
}

// ---------------- kernel 2: conf histogram (top-16 bits of monotone key) ----------------
__global__ void k_hist(const float* p0, const float* p1, const float* p2, uint8_t* ws) {
    int t = blockIdx.x * blockDim.x + threadIdx.x;
    if (t >= M_TOT) return;
    int s, c, H; scale_of(t, s, c, H);
    const float* p = (s == 0) ? p0 : (s == 1) ? p1 : p2;
    float conf = sigf(conf_logit(p, c, H));
    u32 cb = fmono(conf);
    atomicAdd(&((u32*)(ws + OFF_HIST))[s * NBINS + (cb >> 16)], 1u);
}

// ---------------- kernel 3: find 16-bit threshold bin per scale ----------------
__global__ __launch_bounds__(1024) void k_scan(uint8_t* ws) {
    int s = blockIdx.x;
    u32* hist = (u32*)(ws + OFF_HIST) + s * NBINS;
    __shared__ u32 sum[1024];
    int t = threadIdx.x;
    u32 acc = 0;
    for (int b = t * 64; b < t * 64 + 64; ++b) acc += hist[b];
    sum[t] = acc;
    __syncthreads();
    // inclusive suffix scan over thread partials
    for (int off = 1; off < 1024; off <<= 1) {
        u32 v = (t + off < 1024) ? sum[t + off] : 0;
        __syncthreads();
        sum[t] += v;
        __syncthreads();
    }
    u32 excl = (t < 1023) ? sum[t + 1] : 0;       // count in bins above my range
    u32 mine = sum[t] - excl;
    if (excl < K_SEL && excl + mine >= K_SEL) {
        u32 cum = excl; int thr = t * 64;
        for (int b = t * 64 + 63; b >= t * 64; --b) {
            cum += hist[b];
            if (cum >= K_SEL) { thr = b; break; }
        }
        ((u32*)(ws + OFF_THR))[s] = (u32)thr;
    }
}

// ---------------- kernel 4: compact candidates >= threshold bin ----------------
__global__ void k_compact(const float* p0, const float* p1, const float* p2, uint8_t* ws) {
    int t = blockIdx.x * blockDim.x + threadIdx.x;
    if (t >= M_TOT) return;
    int s, c, H; scale_of(t, s, c, H);
    const float* p = (s == 0) ? p0 : (s == 1) ? p1 : p2;
    float conf = sigf(conf_logit(p, c, H));
    u32 cb = fmono(conf);
    if ((cb >> 16) >= ((u32*)(ws + OFF_THR))[s]) {
        u32 pos = atomicAdd(&((u32*)(ws + OFF_CNT))[s], 1u);
        if (pos < CAND_CAP) {
            u64 key = ((u64)cb << 32) | (u32)(~(u32)c);  // ties: smaller c ranks higher
            ((u64*)(ws + OFF_CAND))[s * CAND_CAP + pos] = key;
        }
    }
}

// ---------------- kernel 5: per-scale bitonic sort (next-pow2 >= count), emit top-512 ----------------
__global__ __launch_bounds__(1024) void k_sort3(uint8_t* ws) {
    int s = blockIdx.x;
    __shared__ u64 a[CAND_CAP];
    u32 cnt = ((u32*)(ws + OFF_CNT))[s];
    if (cnt > CAND_CAP) cnt = CAND_CAP;
    int n2 = K_SEL;
    while (n2 < (int)cnt) n2 <<= 1;           // uniform across block (same global read)
    u64* cand = (u64*)(ws + OFF_CAND) + s * CAND_CAP;
    for (int i = threadIdx.x; i < n2; i += 1024) a[i] = (i < (int)cnt) ? cand[i] : 0ull;
    __syncthreads();
    for (int k = 2; k <= n2; k <<= 1) {
        for (int j = k >> 1; j > 0; j >>= 1) {
            for (int i = threadIdx.x; i < n2; i += 1024) {
                int ixj = i ^ j;
                if (ixj > i) {
                    bool desc = ((i & k) == 0);
                    u64 x = a[i], y = a[ixj];
                    if (desc ? (x < y) : (x > y)) { a[i] = y; a[ixj] = x; }
                }
            }
            __syncthreads();
        }
    }
    u64* topk = (u64*)(ws + OFF_TOPK) + s * K_SEL;
    for (int r = threadIdx.x; r < K_SEL; r += 1024) topk[r] = a[r];
}

// ---------------- kernel 6: decode 1536 boxes + NMS sort keys ----------------
__global__ void k_decode(const float* p0, const float* p1, const float* p2,
                         const float* a0, const float* a1, const float* a2, uint8_t* ws) {
    int t = blockIdx.x * 256 + threadIdx.x;
    if (t >= NBOX) return;
    int s = t / K_SEL;
    int H = (s == 0) ? 13 : (s == 1) ? 26 : 52;
    float stride = (s == 0) ? 32.f : (s == 1) ? 16.f : 8.f;
    const float* p = (s == 0) ? p0 : (s == 1) ? p1 : p2;
    const float* anch = (s == 0) ? a0 : (s == 1) ? a1 : a2;
    int HW = H * H, hw3 = HW * 3;
    u64 key = ((u64*)(ws + OFF_TOPK))[t];
    int c = (int)(~(u32)key);
    int n = c / hw3; int rem = c - n * hw3;
    int pix = rem / 3; int a = rem - pix * 3;
    int h = pix / H, w = pix - h * H;
    size_t base = (size_t)(n * 255 + a * 85) * HW + pix;
    float v0 = p[base];
    float v1 = p[base + HW];
    float v2 = p[base + 2 * (size_t)HW];
    float v3 = p[base + 3 * (size_t)HW];
    float v4 = p[base + 4 * (size_t)HW];
    float conf = sigf(v0);
    float cx = ((float)w + sigf(v1)) * stride;
    float cy = ((float)h + sigf(v2)) * stride;
    float bw = anch[a * 2 + 0] * expf(v3);
    float bh = anch[a * 2 + 1] * expf(v4);
    float best = -INFINITY; int bi = 0;
    for (int k2 = 0; k2 < 80; ++k2) {
        float vv = p[base + (size_t)(5 + k2) * HW];
        if (vv > best) { best = vv; bi = k2; }   // first-occurrence argmax
    }
    float* box = (float*)(ws + OFF_BOX) + t * 7;
    box[0] = (float)n; box[1] = conf; box[2] = cx; box[3] = cy;
    box[4] = bw; box[5] = bh; box[6] = (float)bi;
    bool valid = conf > 0.5f;
    u32 mono = valid ? fmono(conf) : fmono(-INFINITY);
    ((u64*)(ws + OFF_SKEY))[t] = ((u64)mono << 32) | (u32)(~(u32)t);  // ties: smaller pos first
}

// ---------------- kernel 7: sort 1536 by score (stable), build sorted arrays ----------------
__global__ __launch_bounds__(1024) void k_sortnms(uint8_t* ws) {
    __shared__ u64 a[2048];
    int t = threadIdx.x;
    u64* skey = (u64*)(ws + OFF_SKEY);
    for (int i = t; i < 2048; i += 1024) a[i] = (i < NBOX) ? skey[i] : 0ull;
    __syncthreads();
    for (int k = 2; k <= 2048; k <<= 1) {
        for (int j = k >> 1; j > 0; j >>= 1) {
            for (int i = t; i < 2048; i += 1024) {
                int ixj = i ^ j;
                if (ixj > i) {
                    bool desc = ((i & k) == 0);
                    u64 x = a[i], y = a[ixj];
                    if (desc ? (x < y) : (x > y)) { a[i] = y; a[ixj] = x; }
                }
            }
            __syncthreads();
        }
    }
    float* box  = (float*)(ws + OFF_BOX);
    float* sbox = (float*)(ws + OFF_SBOX);
    float* geom = (float*)(ws + OFF_GEOM);
    for (int i = t; i < NBOX; i += 1024) {
        int pos = (int)(~(u32)a[i]);
        float b0 = box[pos * 7 + 0], b1 = box[pos * 7 + 1], b2 = box[pos * 7 + 2];
        float b3 = box[pos * 7 + 3], b4 = box[pos * 7 + 4], b5 = box[pos * 7 + 5];
        float b6 = box[pos * 7 + 6];
        sbox[i * 7 + 0] = b0; sbox[i * 7 + 1] = b1; sbox[i * 7 + 2] = b2;
        sbox[i * 7 + 3] = b3; sbox[i * 7 + 4] = b4; sbox[i * 7 + 5] = b5;
        sbox[i * 7 + 6] = b6;
        geom[i]            = b2 - b4 * 0.5f;   // x1
        geom[NBOX + i]     = b3 - b5 * 0.5f;   // y1
        geom[2 * NBOX + i] = b2 + b4 * 0.5f;   // x2
        geom[3 * NBOX + i] = b3 + b5 * 0.5f;   // y2
        geom[4 * NBOX + i] = b4 * b5;          // area
    }
}

// ---------------- kernel 8: per-(image,class)-bucket greedy NMS + output write ----------------
// Greedy NMS with the `same (n,cls)` gate decomposes exactly into independent
// per-bucket chains (suppression never crosses buckets; within a bucket the
// greedy order is the global sorted order restricted to it). Buckets are tiny
// (1536 boxes over 5120 buckets), so each bucket's serial chain is ~1-5 steps.
__global__ __launch_bounds__(1024) void k_nms(uint8_t* ws, float* out) {
    __shared__ float sx1[NBOX], sy1[NBOX], sx2[NBOX], sy2[NBOX], sar[NBOX];
    __shared__ int sbk[NBOX];
    __shared__ uint8_t sval[NBOX], skeep[NBOX];
    float* geom = (float*)(ws + OFF_GEOM);
    float* sbox = (float*)(ws + OFF_SBOX);
    int t = threadIdx.x;
    for (int i = t; i < NBOX; i += 1024) {
        sx1[i] = geom[i];
        sy1[i] = geom[NBOX + i];
        sx2[i] = geom[2 * NBOX + i];
        sy2[i] = geom[3 * NBOX + i];
        sar[i] = geom[4 * NBOX + i];
        float n = sbox[i * 7 + 0], cond = sbox[i * 7 + 1], cls = sbox[i * 7 + 6];
        sbk[i] = (int)n * 80 + (int)cls;     // exact small ints
        sval[i] = (cond > 0.5f) ? 1 : 0;
        skeep[i] = 0;
    }
    __syncthreads();
    for (int i = t; i < NBOX; i += 1024) {
        int b = sbk[i];
        bool leader = true;                  // first member of bucket in sorted order
        for (int j = 0; j < i; ++j) if (sbk[j] == b) { leader = false; break; }
        if (!leader) continue;
        // serial greedy within this bucket; skeep == "active" (valid && !suppressed)
        for (int j = i; j < NBOX; ++j) {
            if (sbk[j] != b) continue;
            bool sup = false;
            for (int j2 = i; j2 < j; ++j2) {
                if (sbk[j2] != b || !skeep[j2]) continue;
                float ix1 = fmaxf(sx1[j2], sx1[j]);
                float iy1 = fmaxf(sy1[j2], sy1[j]);
                float ix2 = fminf(sx2[j2], sx2[j]);
                float iy2 = fminf(sy2[j2], sy2[j]);
                float iw = fmaxf(ix2 - ix1, 0.f), ih = fmaxf(iy2 - iy1, 0.f);
                float inter = iw * ih;
                float iou = inter / (sar[j2] + sar[j] - inter + 1e-9f);
                if (iou > 0.1f) { sup = true; break; }
            }
            skeep[j] = (!sup && sval[j]) ? 1 : 0;
        }
    }
    __syncthreads();
    for (int i = t; i < NBOX; i += 1024) {
        float kf = skeep[i] ? 1.f : 0.f;
        for (int k2 = 0; k2 < 7; ++k2) out[i * 7 + k2] = sbox[i * 7 + k2] * kf;
        out[NBOX * 7 + i] = kf;
    }
}

extern "C" void kernel_launch(void* const* d_in, const int* in_sizes, int n_in,
                              void* d_out, int out_size, void* d_ws, size_t ws_size,
                              hipStream_t stream) {
    const float* p0 = (const float*)d_in[0];
    const float* p1 = (const float*)d_in[1];
    const float* p2 = (const float*)d_in[2];
    const float* a0 = (const float*)d_in[3];
    const float* a1 = (const float*)d_in[4];
    const float* a2 = (const float*)d_in[5];
    uint8_t* ws = (uint8_t*)d_ws;
    float* out = (float*)d_out;

    const int GB = (M_TOT + 255) / 256;  // 2662

    k_zero   <<<768, 256, 0, stream>>>(ws);
    k_hist   <<<GB, 256, 0, stream>>>(p0, p1, p2, ws);
    k_scan   <<<3, 1024, 0, stream>>>(ws);
    k_compact<<<GB, 256, 0, stream>>>(p0, p1, p2, ws);
    k_sort3  <<<3, 1024, 0, stream>>>(ws);
    k_decode <<<6, 256, 0, stream>>>(p0, p1, p2, a0, a1, a2, ws);
    k_sortnms<<<1, 1024, 0, stream>>>(ws);
    k_nms    <<<1, 1024, 0, stream>>>(ws, out);
}

// Round 3
// 518.196 us; speedup vs baseline: 4.4051x; 4.4051x over previous
//
#include <hip/hip_runtime.h>
#include <stdint.h>

#define K_SEL 512
#define NBOX 1536          // 3 * K_SEL
#define CAND_CAP 4096
#define NBINS 65536
#define NBUCK 5120         // 64 images * 80 classes
#define BCAP 32            // max tracked members per (image,class) bucket

// scale params
#define M0 32448           // 64*13*13*3
#define M1 129792          // 64*26*26*3
#define M2 519168          // 64*52*52*3
#define M_TOT (M0+M1+M2)   // 681408

// ws byte offsets
#define OFF_HIST 0u           // 3*65536*4 = 786432
#define OFF_CNT  786432u      // 3*4
#define OFF_THR  786448u      // 3*4
#define OFF_CAND 786464u      // 3*4096*8 = 98304 -> 884768
#define OFF_TOPK 884768u      // 1536*8 -> 897056
#define OFF_BOX  897056u      // 1536*7*4 -> 940064
#define OFF_SKEY 940064u      // 1536*8 -> 952352
#define OFF_SBOX 952352u      // 1536*7*4 -> 995360
#define OFF_GEOM 995360u      // 5*1536*4 -> 1026080
#define OFF_SBK  1026080u     // 1536*4 -> 1032224
#define OFF_BCNT 1032224u     // 5120*4 -> 1052704
#define OFF_KEEP 1052704u     // 1536*4 -> 1058848
#define OFF_MEMB 1058848u     // 5120*32*2 -> 1386528

typedef unsigned long long u64;
typedef uint32_t u32;
typedef uint16_t u16;

__device__ __forceinline__ float sigf(float x) { return 1.0f / (1.0f + expf(-x)); }

__device__ __forceinline__ u32 fmono(float f) {
    u32 u = __float_as_uint(f);
    return (u & 0x80000000u) ? ~u : (u | 0x80000000u);
}

// map flat thread t over all scales -> (s, c, H)
__device__ __forceinline__ void scale_of(int t, int& s, int& c, int& H) {
    if (t < M0)            { s = 0; c = t;           H = 13; }
    else if (t < M0 + M1)  { s = 1; c = t - M0;      H = 26; }
    else                   { s = 2; c = t - M0 - M1; H = 52; }
}

__device__ __forceinline__ float conf_logit(const float* p, int c, int H) {
    int HW = H * H;
    int hw3 = HW * 3;
    int n = c / hw3; int rem = c - n * hw3;
    int pix = rem / 3; int a = rem - pix * 3;
    return p[(size_t)(n * 255 + a * 85) * HW + pix];
}

// ---------------- kernel 1: zero scratch ----------------
__global__ void k_zero(uint8_t* ws) {
    u32* hist = (u32*)(ws + OFF_HIST);
    int t = blockIdx.x * blockDim.x + threadIdx.x;
    if (t < 3 * NBINS) hist[t] = 0;
    if (t < 3) ((u32*)(ws + OFF_CNT))[t] = 0;
    if (t < NBUCK) ((u32*)(ws + OFF_BCNT))[t] = 0;
    if (t < NBOX) ((u32*)(ws + OFF_KEEP))[t] = 0;
}

// ---------------- kernel 2: conf histogram (top-16 bits of monotone key) ----------------
__global__ void k_hist(const float* p0, const float* p1, const float* p2, uint8_t* ws) {
    int t = blockIdx.x * blockDim.x + threadIdx.x;
    if (t >= M_TOT) return;
    int s, c, H; scale_of(t, s, c, H);
    const float* p = (s == 0) ? p0 : (s == 1) ? p1 : p2;
    float conf = sigf(conf_logit(p, c, H));
    u32 cb = fmono(conf);
    atomicAdd(&((u32*)(ws + OFF_HIST))[s * NBINS + (cb >> 16)], 1u);
}

// ---------------- kernel 3: find 16-bit threshold bin per scale ----------------
__global__ __launch_bounds__(1024) void k_scan(uint8_t* ws) {
    int s = blockIdx.x;
    u32* hist = (u32*)(ws + OFF_HIST) + s * NBINS;
    __shared__ u32 sum[1024];
    int t = threadIdx.x;
    u32 acc = 0;
    for (int b = t * 64; b < t * 64 + 64; ++b) acc += hist[b];
    sum[t] = acc;
    __syncthreads();
    // inclusive suffix scan over thread partials
    for (int off = 1; off < 1024; off <<= 1) {
        u32 v = (t + off < 1024) ? sum[t + off] : 0;
        __syncthreads();
        sum[t] += v;
        __syncthreads();
    }
    u32 excl = (t < 1023) ? sum[t + 1] : 0;       // count in bins above my range
    u32 mine = sum[t] - excl;
    if (excl < K_SEL && excl + mine >= K_SEL) {
        u32 cum = excl; int thr = t * 64;
        for (int b = t * 64 + 63; b >= t * 64; --b) {
            cum += hist[b];
            if (cum >= K_SEL) { thr = b; break; }
        }
        ((u32*)(ws + OFF_THR))[s] = (u32)thr;
    }
}

// ---------------- kernel 4: compact candidates >= threshold bin ----------------
__global__ void k_compact(const float* p0, const float* p1, const float* p2, uint8_t* ws) {
    int t = blockIdx.x * blockDim.x + threadIdx.x;
    if (t >= M_TOT) return;
    int s, c, H; scale_of(t, s, c, H);
    const float* p = (s == 0) ? p0 : (s == 1) ? p1 : p2;
    float conf = sigf(conf_logit(p, c, H));
    u32 cb = fmono(conf);
    if ((cb >> 16) >= ((u32*)(ws + OFF_THR))[s]) {
        u32 pos = atomicAdd(&((u32*)(ws + OFF_CNT))[s], 1u);
        if (pos < CAND_CAP) {
            u64 key = ((u64)cb << 32) | (u32)(~(u32)c);  // ties: smaller c ranks higher
            ((u64*)(ws + OFF_CAND))[s * CAND_CAP + pos] = key;
        }
    }
}

// ---------------- kernel 5: per-scale bitonic sort (next-pow2 >= count), emit top-512 ----------------
__global__ __launch_bounds__(1024) void k_sort3(uint8_t* ws) {
    int s = blockIdx.x;
    __shared__ u64 a[CAND_CAP];
    u32 cnt = ((u32*)(ws + OFF_CNT))[s];
    if (cnt > CAND_CAP) cnt = CAND_CAP;
    int n2 = K_SEL;
    while (n2 < (int)cnt) n2 <<= 1;           // uniform across block (same global read)
    u64* cand = (u64*)(ws + OFF_CAND) + s * CAND_CAP;
    for (int i = threadIdx.x; i < n2; i += 1024) a[i] = (i < (int)cnt) ? cand[i] : 0ull;
    __syncthreads();
    for (int k = 2; k <= n2; k <<= 1) {
        for (int j = k >> 1; j > 0; j >>= 1) {
            for (int i = threadIdx.x; i < n2; i += 1024) {
                int ixj = i ^ j;
                if (ixj > i) {
                    bool desc = ((i & k) == 0);
                    u64 x = a[i], y = a[ixj];
                    if (desc ? (x < y) : (x > y)) { a[i] = y; a[ixj] = x; }
                }
            }
            __syncthreads();
        }
    }
    u64* topk = (u64*)(ws + OFF_TOPK) + s * K_SEL;
    for (int r = threadIdx.x; r < K_SEL; r += 1024) topk[r] = a[r];
}

// ---------------- kernel 6: decode 1536 boxes + NMS sort keys ----------------
__global__ void k_decode(const float* p0, const float* p1, const float* p2,
                         const float* a0, const float* a1, const float* a2, uint8_t* ws) {
    int t = blockIdx.x * 256 + threadIdx.x;
    if (t >= NBOX) return;
    int s = t / K_SEL;
    int H = (s == 0) ? 13 : (s == 1) ? 26 : 52;
    float stride = (s == 0) ? 32.f : (s == 1) ? 16.f : 8.f;
    const float* p = (s == 0) ? p0 : (s == 1) ? p1 : p2;
    const float* anch = (s == 0) ? a0 : (s == 1) ? a1 : a2;
    int HW = H * H, hw3 = HW * 3;
    u64 key = ((u64*)(ws + OFF_TOPK))[t];
    int c = (int)(~(u32)key);
    int n = c / hw3; int rem = c - n * hw3;
    int pix = rem / 3; int a = rem - pix * 3;
    int h = pix / H, w = pix - h * H;
    size_t base = (size_t)(n * 255 + a * 85) * HW + pix;
    float v0 = p[base];
    float v1 = p[base + HW];
    float v2 = p[base + 2 * (size_t)HW];
    float v3 = p[base + 3 * (size_t)HW];
    float v4 = p[base + 4 * (size_t)HW];
    float conf = sigf(v0);
    float cx = ((float)w + sigf(v1)) * stride;
    float cy = ((float)h + sigf(v2)) * stride;
    float bw = anch[a * 2 + 0] * expf(v3);
    float bh = anch[a * 2 + 1] * expf(v4);
    float best = -INFINITY; int bi = 0;
    for (int k2 = 0; k2 < 80; ++k2) {
        float vv = p[base + (size_t)(5 + k2) * HW];
        if (vv > best) { best = vv; bi = k2; }   // first-occurrence argmax
    }
    float* box = (float*)(ws + OFF_BOX) + t * 7;
    box[0] = (float)n; box[1] = conf; box[2] = cx; box[3] = cy;
    box[4] = bw; box[5] = bh; box[6] = (float)bi;
    bool valid = conf > 0.5f;
    u32 mono = valid ? fmono(conf) : fmono(-INFINITY);
    ((u64*)(ws + OFF_SKEY))[t] = ((u64)mono << 32) | (u32)(~(u32)t);  // ties: smaller pos first
}

// ---------------- kernel 7: sort 1536 by score (stable), build sorted arrays ----------------
__global__ __launch_bounds__(1024) void k_sortnms(uint8_t* ws) {
    __shared__ u64 a[2048];
    int t = threadIdx.x;
    u64* skey = (u64*)(ws + OFF_SKEY);
    for (int i = t; i < 2048; i += 1024) a[i] = (i < NBOX) ? skey[i] : 0ull;
    __syncthreads();
    for (int k = 2; k <= 2048; k <<= 1) {
        for (int j = k >> 1; j > 0; j >>= 1) {
            for (int i = t; i < 2048; i += 1024) {
                int ixj = i ^ j;
                if (ixj > i) {
                    bool desc = ((i & k) == 0);
                    u64 x = a[i], y = a[ixj];
                    if (desc ? (x < y) : (x > y)) { a[i] = y; a[ixj] = x; }
                }
            }
            __syncthreads();
        }
    }
    float* box  = (float*)(ws + OFF_BOX);
    float* sbox = (float*)(ws + OFF_SBOX);
    float* geom = (float*)(ws + OFF_GEOM);
    int*   sbk  = (int*)(ws + OFF_SBK);
    for (int i = t; i < NBOX; i += 1024) {
        int pos = (int)(~(u32)a[i]);
        float b0 = box[pos * 7 + 0], b1 = box[pos * 7 + 1], b2 = box[pos * 7 + 2];
        float b3 = box[pos * 7 + 3], b4 = box[pos * 7 + 4], b5 = box[pos * 7 + 5];
        float b6 = box[pos * 7 + 6];
        sbox[i * 7 + 0] = b0; sbox[i * 7 + 1] = b1; sbox[i * 7 + 2] = b2;
        sbox[i * 7 + 3] = b3; sbox[i * 7 + 4] = b4; sbox[i * 7 + 5] = b5;
        sbox[i * 7 + 6] = b6;
        geom[i]            = b2 - b4 * 0.5f;   // x1
        geom[NBOX + i]     = b3 - b5 * 0.5f;   // y1
        geom[2 * NBOX + i] = b2 + b4 * 0.5f;   // x2
        geom[3 * NBOX + i] = b3 + b5 * 0.5f;   // y2
        geom[4 * NBOX + i] = b4 * b5;          // area
        sbk[i] = (int)b0 * 80 + (int)b6;       // (image, class) bucket id, exact small ints
    }
}

// ---------------- kernel 8: per-box in-bucket rank -> bucket member lists ----------------
// rank[i] = #{j < i : bucket[j] == bucket[i]} over the sorted order. No-break
// counting loop: fully pipelined LDS reads, spread over 6 blocks.
__global__ __launch_bounds__(256) void k_rank(uint8_t* ws) {
    __shared__ u16 lbk[NBOX];
    int* sbk = (int*)(ws + OFF_SBK);
    for (int i = threadIdx.x; i < NBOX; i += 256) lbk[i] = (u16)sbk[i];
    __syncthreads();
    int i = blockIdx.x * 256 + threadIdx.x;
    if (i >= NBOX) return;
    u16 b = lbk[i];
    int r = 0;
    for (int j = 0; j < i; ++j) r += (lbk[j] == b) ? 1 : 0;
    atomicAdd(&((u32*)(ws + OFF_BCNT))[b], 1u);
    if (r < BCAP) ((u16*)(ws + OFF_MEMB))[(u32)b * BCAP + r] = (u16)i;  // unique slot
}

// ---------------- kernel 9: per-bucket serial greedy NMS ----------------
// One thread per (image,class) bucket; members already in sorted order.
__global__ __launch_bounds__(256) void k_bucket(uint8_t* ws) {
    int b = blockIdx.x * 256 + threadIdx.x;
    if (b >= NBUCK) return;
    u32 cnt = ((u32*)(ws + OFF_BCNT))[b];
    if (cnt == 0) return;
    if (cnt > BCAP) cnt = BCAP;
    const u16* memb = (const u16*)(ws + OFF_MEMB) + (u32)b * BCAP;
    const float* geom = (const float*)(ws + OFF_GEOM);
    const float* sbox = (const float*)(ws + OFF_SBOX);
    u32* keep = (u32*)(ws + OFF_KEEP);
    u32 keptMask = 0;
    for (u32 r = 0; r < cnt; ++r) {
        int i = memb[r];
        float x1 = geom[i], y1 = geom[NBOX + i];
        float x2 = geom[2 * NBOX + i], y2 = geom[3 * NBOX + i];
        float ar = geom[4 * NBOX + i];
        bool val = sbox[i * 7 + 1] > 0.5f;
        bool sup = false;
        for (u32 r2 = 0; r2 < r; ++r2) {
            if (!((keptMask >> r2) & 1u)) continue;   // only active boxes suppress
            int j = memb[r2];
            float ix1 = fmaxf(x1, geom[j]);
            float iy1 = fmaxf(y1, geom[NBOX + j]);
            float ix2 = fminf(x2, geom[2 * NBOX + j]);
            float iy2 = fminf(y2, geom[3 * NBOX + j]);
            float iw = fmaxf(ix2 - ix1, 0.f), ih = fmaxf(iy2 - iy1, 0.f);
            float inter = iw * ih;
            float iou = inter / (ar + geom[4 * NBOX + j] - inter + 1e-9f);
            if (iou > 0.1f) { sup = true; break; }
        }
        bool kept = val && !sup;
        if (kept) keptMask |= (1u << r);
        keep[i] = kept ? 1u : 0u;
    }
}

// ---------------- kernel 10: write outputs ----------------
__global__ void k_out(uint8_t* ws, float* out) {
    int i = blockIdx.x * 256 + threadIdx.x;
    if (i >= NBOX) return;
    float kf = ((u32*)(ws + OFF_KEEP))[i] ? 1.f : 0.f;
    const float* sbox = (const float*)(ws + OFF_SBOX) + i * 7;
    float* o = out + i * 7;
    for (int k2 = 0; k2 < 7; ++k2) o[k2] = sbox[k2] * kf;
    out[NBOX * 7 + i] = kf;
}

extern "C" void kernel_launch(void* const* d_in, const int* in_sizes, int n_in,
                              void* d_out, int out_size, void* d_ws, size_t ws_size,
                              hipStream_t stream) {
    const float* p0 = (const float*)d_in[0];
    const float* p1 = (const float*)d_in[1];
    const float* p2 = (const float*)d_in[2];
    const float* a0 = (const float*)d_in[3];
    const float* a1 = (const float*)d_in[4];
    const float* a2 = (const float*)d_in[5];
    uint8_t* ws = (uint8_t*)d_ws;
    float* out = (float*)d_out;

    const int GB = (M_TOT + 255) / 256;  // 2662

    k_zero   <<<768, 256, 0, stream>>>(ws);
    k_hist   <<<GB, 256, 0, stream>>>(p0, p1, p2, ws);
    k_scan   <<<3, 1024, 0, stream>>>(ws);
    k_compact<<<GB, 256, 0, stream>>>(p0, p1, p2, ws);
    k_sort3  <<<3, 1024, 0, stream>>>(ws);
    k_decode <<<6, 256, 0, stream>>>(p0, p1, p2, a0, a1, a2, ws);
    k_sortnms<<<1, 1024, 0, stream>>>(ws);
    k_rank   <<<6, 256, 0, stream>>>(ws);
    k_bucket <<<20, 256, 0, stream>>>(ws);
    k_out    <<<6, 256, 0, stream>>>(ws, out);
}

// Round 4
// 282.256 us; speedup vs baseline: 8.0873x; 1.8359x over previous
//
#include <hip/hip_runtime.h>
#include <stdint.h>

#define K_SEL 512
#define NBOX 1536          // 3 * K_SEL
#define CAND_CAP 4096
#define HBITS 13
#define HBINS 8192         // 13-bit monotone-key histogram (32 KB LDS)
#define NBUCK 5120         // 64 images * 80 classes
#define BCAP 32            // max tracked members per (image,class) bucket

// scale params
#define M0 32448           // 64*13*13*3
#define M1 129792          // 64*26*26*3
#define M2 519168          // 64*52*52*3
#define M_TOT (M0+M1+M2)   // 681408

// ws byte offsets
#define OFF_HIST 0u           // 3*8192*4 = 98304
#define OFF_CNT  786432u      // 3*4
#define OFF_THR  786448u      // 3*4
#define OFF_CAND 786464u      // 3*4096*8 = 98304 -> 884768
#define OFF_TOPK 884768u      // 1536*8 -> 897056
#define OFF_BOX  897056u      // 1536*7*4 -> 940064
#define OFF_SKEY 940064u      // 1536*8 -> 952352
#define OFF_SBOX 952352u      // 1536*7*4 -> 995360
#define OFF_GEOM 995360u      // 5*1536*4 -> 1026080
#define OFF_SBK  1026080u     // 1536*4 -> 1032224
#define OFF_BCNT 1032224u     // 5120*4 -> 1052704
#define OFF_KEEP 1052704u     // 1536*4 -> 1058848
#define OFF_MEMB 1058848u     // 5120*32*2 -> 1386528

typedef unsigned long long u64;
typedef uint32_t u32;
typedef uint16_t u16;

__device__ __forceinline__ float sigf(float x) { return 1.0f / (1.0f + expf(-x)); }

__device__ __forceinline__ u32 fmono(float f) {
    u32 u = __float_as_uint(f);
    return (u & 0x80000000u) ? ~u : (u | 0x80000000u);
}

// map flat thread t over all scales -> (s, c, H)
__device__ __forceinline__ void scale_of(int t, int& s, int& c, int& H) {
    if (t < M0)            { s = 0; c = t;           H = 13; }
    else if (t < M0 + M1)  { s = 1; c = t - M0;      H = 26; }
    else                   { s = 2; c = t - M0 - M1; H = 52; }
}

__device__ __forceinline__ float conf_logit(const float* p, int c, int H) {
    int HW = H * H;
    int hw3 = HW * 3;
    int n = c / hw3; int rem = c - n * hw3;
    int pix = rem / 3; int a = rem - pix * 3;
    return p[(size_t)(n * 255 + a * 85) * HW + pix];
}

// ---------------- kernel 1: zero scratch ----------------
__global__ void k_zero(uint8_t* ws) {
    int t = blockIdx.x * blockDim.x + threadIdx.x;
    if (t < 3 * HBINS) ((u32*)(ws + OFF_HIST))[t] = 0;
    if (t < 3) ((u32*)(ws + OFF_CNT))[t] = 0;
    if (t < NBUCK) ((u32*)(ws + OFF_BCNT))[t] = 0;
    if (t < NBOX) ((u32*)(ws + OFF_KEEP))[t] = 0;
}

// ---------------- kernel 2: per-block LDS histogram -> coalesced global merge ----------------
// Same-address atomic storms go to LDS (cheap, per-CU); the global merge is a
// lane->bin coalesced sweep with distinct addresses (parallel at L2).
__global__ __launch_bounds__(256) void k_hist(const float* p0, const float* p1, const float* p2,
                                              uint8_t* ws) {
    __shared__ u32 lh[HBINS];
    for (int i = threadIdx.x; i < HBINS; i += 256) lh[i] = 0;
    __syncthreads();
    int b = blockIdx.x, s, b0, nb;
    if (b < 8)       { s = 0; b0 = b;      nb = 8;  }
    else if (b < 32) { s = 1; b0 = b - 8;  nb = 24; }
    else             { s = 2; b0 = b - 32; nb = 64; }
    int M = (s == 0) ? M0 : (s == 1) ? M1 : M2;
    int H = (s == 0) ? 13 : (s == 1) ? 26 : 52;
    const float* p = (s == 0) ? p0 : (s == 1) ? p1 : p2;
    for (int c = b0 * 256 + threadIdx.x; c < M; c += nb * 256) {
        float conf = sigf(conf_logit(p, c, H));
        atomicAdd(&lh[fmono(conf) >> (32 - HBITS)], 1u);
    }
    __syncthreads();
    u32* gh = (u32*)(ws + OFF_HIST) + s * HBINS;
    for (int i = threadIdx.x; i < HBINS; i += 256) {
        u32 v = lh[i];
        if (v) atomicAdd(&gh[i], v);
    }
}

// ---------------- kernel 3: find threshold bin per scale (suffix scan of 8192 bins) ----------------
__global__ __launch_bounds__(1024) void k_scan(uint8_t* ws) {
    int s = blockIdx.x;
    u32* hist = (u32*)(ws + OFF_HIST) + s * HBINS;
    __shared__ u32 sum[1024];
    int t = threadIdx.x;
    u32 acc = 0;
    for (int b = t * 8; b < t * 8 + 8; ++b) acc += hist[b];
    sum[t] = acc;
    __syncthreads();
    // inclusive suffix scan over thread partials
    for (int off = 1; off < 1024; off <<= 1) {
        u32 v = (t + off < 1024) ? sum[t + off] : 0;
        __syncthreads();
        sum[t] += v;
        __syncthreads();
    }
    u32 excl = (t < 1023) ? sum[t + 1] : 0;       // count in bins above my range
    u32 mine = sum[t] - excl;
    if (excl < K_SEL && excl + mine >= K_SEL) {
        u32 cum = excl; int thr = t * 8;
        for (int b = t * 8 + 7; b >= t * 8; --b) {
            cum += hist[b];
            if (cum >= K_SEL) { thr = b; break; }
        }
        ((u32*)(ws + OFF_THR))[s] = (u32)thr;
    }
}

// ---------------- kernel 4: compact candidates >= threshold bin ----------------
__global__ void k_compact(const float* p0, const float* p1, const float* p2, uint8_t* ws) {
    int t = blockIdx.x * blockDim.x + threadIdx.x;
    if (t >= M_TOT) return;
    int s, c, H; scale_of(t, s, c, H);
    const float* p = (s == 0) ? p0 : (s == 1) ? p1 : p2;
    float conf = sigf(conf_logit(p, c, H));
    u32 cb = fmono(conf);
    if ((cb >> (32 - HBITS)) >= ((u32*)(ws + OFF_THR))[s]) {
        u32 pos = atomicAdd(&((u32*)(ws + OFF_CNT))[s], 1u);
        if (pos < CAND_CAP) {
            u64 key = ((u64)cb << 32) | (u32)(~(u32)c);  // ties: smaller c ranks higher
            ((u64*)(ws + OFF_CAND))[s * CAND_CAP + pos] = key;
        }
    }
}

// ---------------- kernel 5: per-scale bitonic sort (next-pow2 >= count), emit top-512 ----------------
__global__ __launch_bounds__(1024) void k_sort3(uint8_t* ws) {
    int s = blockIdx.x;
    __shared__ u64 a[CAND_CAP];
    u32 cnt = ((u32*)(ws + OFF_CNT))[s];
    if (cnt > CAND_CAP) cnt = CAND_CAP;
    int n2 = K_SEL;
    while (n2 < (int)cnt) n2 <<= 1;           // uniform across block (same global read)
    u64* cand = (u64*)(ws + OFF_CAND) + s * CAND_CAP;
    for (int i = threadIdx.x; i < n2; i += 1024) a[i] = (i < (int)cnt) ? cand[i] : 0ull;
    __syncthreads();
    for (int k = 2; k <= n2; k <<= 1) {
        for (int j = k >> 1; j > 0; j >>= 1) {
            for (int i = threadIdx.x; i < n2; i += 1024) {
                int ixj = i ^ j;
                if (ixj > i) {
                    bool desc = ((i & k) == 0);
                    u64 x = a[i], y = a[ixj];
                    if (desc ? (x < y) : (x > y)) { a[i] = y; a[ixj] = x; }
                }
            }
            __syncthreads();
        }
    }
    u64* topk = (u64*)(ws + OFF_TOPK) + s * K_SEL;
    for (int r = threadIdx.x; r < K_SEL; r += 1024) topk[r] = a[r];
}

// ---------------- kernel 6: decode 1536 boxes + NMS sort keys ----------------
__global__ void k_decode(const float* p0, const float* p1, const float* p2,
                         const float* a0, const float* a1, const float* a2, uint8_t* ws) {
    int t = blockIdx.x * 256 + threadIdx.x;
    if (t >= NBOX) return;
    int s = t / K_SEL;
    int H = (s == 0) ? 13 : (s == 1) ? 26 : 52;
    float stride = (s == 0) ? 32.f : (s == 1) ? 16.f : 8.f;
    const float* p = (s == 0) ? p0 : (s == 1) ? p1 : p2;
    const float* anch = (s == 0) ? a0 : (s == 1) ? a1 : a2;
    int HW = H * H, hw3 = HW * 3;
    u64 key = ((u64*)(ws + OFF_TOPK))[t];
    int c = (int)(~(u32)key);
    int n = c / hw3; int rem = c - n * hw3;
    int pix = rem / 3; int a = rem - pix * 3;
    int h = pix / H, w = pix - h * H;
    size_t base = (size_t)(n * 255 + a * 85) * HW + pix;
    float v0 = p[base];
    float v1 = p[base + HW];
    float v2 = p[base + 2 * (size_t)HW];
    float v3 = p[base + 3 * (size_t)HW];
    float v4 = p[base + 4 * (size_t)HW];
    float conf = sigf(v0);
    float cx = ((float)w + sigf(v1)) * stride;
    float cy = ((float)h + sigf(v2)) * stride;
    float bw = anch[a * 2 + 0] * expf(v3);
    float bh = anch[a * 2 + 1] * expf(v4);
    float best = -INFINITY; int bi = 0;
    for (int k2 = 0; k2 < 80; ++k2) {
        float vv = p[base + (size_t)(5 + k2) * HW];
        if (vv > best) { best = vv; bi = k2; }   // first-occurrence argmax
    }
    float* box = (float*)(ws + OFF_BOX) + t * 7;
    box[0] = (float)n; box[1] = conf; box[2] = cx; box[3] = cy;
    box[4] = bw; box[5] = bh; box[6] = (float)bi;
    bool valid = conf > 0.5f;
    u32 mono = valid ? fmono(conf) : fmono(-INFINITY);
    ((u64*)(ws + OFF_SKEY))[t] = ((u64)mono << 32) | (u32)(~(u32)t);  // ties: smaller pos first
}

// ---------------- kernel 7: sort 1536 by score (stable), build sorted arrays ----------------
__global__ __launch_bounds__(1024) void k_sortnms(uint8_t* ws) {
    __shared__ u64 a[2048];
    int t = threadIdx.x;
    u64* skey = (u64*)(ws + OFF_SKEY);
    for (int i = t; i < 2048; i += 1024) a[i] = (i < NBOX) ? skey[i] : 0ull;
    __syncthreads();
    for (int k = 2; k <= 2048; k <<= 1) {
        for (int j = k >> 1; j > 0; j >>= 1) {
            for (int i = t; i < 2048; i += 1024) {
                int ixj = i ^ j;
                if (ixj > i) {
                    bool desc = ((i & k) == 0);
                    u64 x = a[i], y = a[ixj];
                    if (desc ? (x < y) : (x > y)) { a[i] = y; a[ixj] = x; }
                }
            }
            __syncthreads();
        }
    }
    float* box  = (float*)(ws + OFF_BOX);
    float* sbox = (float*)(ws + OFF_SBOX);
    float* geom = (float*)(ws + OFF_GEOM);
    int*   sbk  = (int*)(ws + OFF_SBK);
    for (int i = t; i < NBOX; i += 1024) {
        int pos = (int)(~(u32)a[i]);
        float b0 = box[pos * 7 + 0], b1 = box[pos * 7 + 1], b2 = box[pos * 7 + 2];
        float b3 = box[pos * 7 + 3], b4 = box[pos * 7 + 4], b5 = box[pos * 7 + 5];
        float b6 = box[pos * 7 + 6];
        sbox[i * 7 + 0] = b0; sbox[i * 7 + 1] = b1; sbox[i * 7 + 2] = b2;
        sbox[i * 7 + 3] = b3; sbox[i * 7 + 4] = b4; sbox[i * 7 + 5] = b5;
        sbox[i * 7 + 6] = b6;
        geom[i]            = b2 - b4 * 0.5f;   // x1
        geom[NBOX + i]     = b3 - b5 * 0.5f;   // y1
        geom[2 * NBOX + i] = b2 + b4 * 0.5f;   // x2
        geom[3 * NBOX + i] = b3 + b5 * 0.5f;   // y2
        geom[4 * NBOX + i] = b4 * b5;          // area
        sbk[i] = (int)b0 * 80 + (int)b6;       // (image, class) bucket id, exact small ints
    }
}

// ---------------- kernel 8: per-box in-bucket rank -> bucket member lists ----------------
__global__ __launch_bounds__(256) void k_rank(uint8_t* ws) {
    __shared__ u16 lbk[NBOX];
    int* sbk = (int*)(ws + OFF_SBK);
    for (int i = threadIdx.x; i < NBOX; i += 256) lbk[i] = (u16)sbk[i];
    __syncthreads();
    int i = blockIdx.x * 256 + threadIdx.x;
    if (i >= NBOX) return;
    u16 b = lbk[i];
    int r = 0;
    for (int j = 0; j < i; ++j) r += (lbk[j] == b) ? 1 : 0;   // no-break, pipelined
    atomicAdd(&((u32*)(ws + OFF_BCNT))[b], 1u);
    if (r < BCAP) ((u16*)(ws + OFF_MEMB))[(u32)b * BCAP + r] = (u16)i;  // unique slot
}

// ---------------- kernel 9: per-bucket serial greedy NMS ----------------
__global__ __launch_bounds__(256) void k_bucket(uint8_t* ws) {
    int b = blockIdx.x * 256 + threadIdx.x;
    if (b >= NBUCK) return;
    u32 cnt = ((u32*)(ws + OFF_BCNT))[b];
    if (cnt == 0) return;
    if (cnt > BCAP) cnt = BCAP;
    const u16* memb = (const u16*)(ws + OFF_MEMB) + (u32)b * BCAP;
    const float* geom = (const float*)(ws + OFF_GEOM);
    const float* sbox = (const float*)(ws + OFF_SBOX);
    u32* keep = (u32*)(ws + OFF_KEEP);
    u32 keptMask = 0;
    for (u32 r = 0; r < cnt; ++r) {
        int i = memb[r];
        float x1 = geom[i], y1 = geom[NBOX + i];
        float x2 = geom[2 * NBOX + i], y2 = geom[3 * NBOX + i];
        float ar = geom[4 * NBOX + i];
        bool val = sbox[i * 7 + 1] > 0.5f;
        bool sup = false;
        for (u32 r2 = 0; r2 < r; ++r2) {
            if (!((keptMask >> r2) & 1u)) continue;   // only active boxes suppress
            int j = memb[r2];
            float ix1 = fmaxf(x1, geom[j]);
            float iy1 = fmaxf(y1, geom[NBOX + j]);
            float ix2 = fminf(x2, geom[2 * NBOX + j]);
            float iy2 = fminf(y2, geom[3 * NBOX + j]);
            float iw = fmaxf(ix2 - ix1, 0.f), ih = fmaxf(iy2 - iy1, 0.f);
            float inter = iw * ih;
            float iou = inter / (ar + geom[4 * NBOX + j] - inter + 1e-9f);
            if (iou > 0.1f) { sup = true; break; }
        }
        bool kept = val && !sup;
        if (kept) keptMask |= (1u << r);
        keep[i] = kept ? 1u : 0u;
    }
}

// ---------------- kernel 10: write outputs ----------------
__global__ void k_out(uint8_t* ws, float* out) {
    int i = blockIdx.x * 256 + threadIdx.x;
    if (i >= NBOX) return;
    float kf = ((u32*)(ws + OFF_KEEP))[i] ? 1.f : 0.f;
    const float* sbox = (const float*)(ws + OFF_SBOX) + i * 7;
    float* o = out + i * 7;
    for (int k2 = 0; k2 < 7; ++k2) o[k2] = sbox[k2] * kf;
    out[NBOX * 7 + i] = kf;
}

extern "C" void kernel_launch(void* const* d_in, const int* in_sizes, int n_in,
                              void* d_out, int out_size, void* d_ws, size_t ws_size,
                              hipStream_t stream) {
    const float* p0 = (const float*)d_in[0];
    const float* p1 = (const float*)d_in[1];
    const float* p2 = (const float*)d_in[2];
    const float* a0 = (const float*)d_in[3];
    const float* a1 = (const float*)d_in[4];
    const float* a2 = (const float*)d_in[5];
    uint8_t* ws = (uint8_t*)d_ws;
    float* out = (float*)d_out;

    const int GB = (M_TOT + 255) / 256;  // 2662

    k_zero   <<<128, 256, 0, stream>>>(ws);
    k_hist   <<<96, 256, 0, stream>>>(p0, p1, p2, ws);
    k_scan   <<<3, 1024, 0, stream>>>(ws);
    k_compact<<<GB, 256, 0, stream>>>(p0, p1, p2, ws);
    k_sort3  <<<3, 1024, 0, stream>>>(ws);
    k_decode <<<6, 256, 0, stream>>>(p0, p1, p2, a0, a1, a2, ws);
    k_sortnms<<<1, 1024, 0, stream>>>(ws);
    k_rank   <<<6, 256, 0, stream>>>(ws);
    k_bucket <<<20, 256, 0, stream>>>(ws);
    k_out    <<<6, 256, 0, stream>>>(ws, out);
}

// Round 5
// 179.614 us; speedup vs baseline: 12.7088x; 1.5715x over previous
//
#include <hip/hip_runtime.h>
#include <stdint.h>

#define K_SEL 512
#define NBOX 1536          // 3 * K_SEL
#define CAND_CAP 4096
#define HBITS 13
#define HBINS 8192         // 13-bit monotone-key histogram (32 KB LDS)
#define NSHARD 128         // candidate-counter shards per scale
#define SEG 64             // entries per shard segment
#define NBUCK 5120         // 64 images * 80 classes
#define BCAP 32            // max tracked members per (image,class) bucket

// scale params
#define M0 32448           // 64*13*13*3
#define M1 129792          // 64*26*26*3
#define M2 519168          // 64*52*52*3
#define M_TOT (M0+M1+M2)   // 681408

// ws byte offsets (16-aligned)
#define OFF_HIST 0u           // 3*8192*4 = 98304
#define OFF_CNT  98304u       // 3*128*4 = 1536 -> 99840
#define OFF_THR  99840u       // 16 -> 99856
#define OFF_CAND 99856u       // 3*128*64*8 = 196608 -> 296464
#define OFF_TOPK 296464u      // 1536*8 -> 308752
#define OFF_BOX  308752u      // 1536*7*4 -> 351760
#define OFF_SKEY 351760u      // 1536*8 -> 364048
#define OFF_SBOX 364048u      // 1536*7*4 -> 407056
#define OFF_GEOM 407056u      // 5*1536*4 -> 437776
#define OFF_SBK  437776u      // 1536*4 -> 443920
#define OFF_BCNT 443920u      // 5120*4 -> 464400
#define OFF_KEEP 464400u      // 1536*4 -> 470544
#define OFF_MEMB 470544u      // 5120*32*2 -> 798224
#define OFF_CB   798224u      // 681408*4 -> 3523856

typedef unsigned long long u64;
typedef uint32_t u32;
typedef uint16_t u16;

__device__ __forceinline__ float sigf(float x) { return 1.0f / (1.0f + expf(-x)); }

__device__ __forceinline__ u32 fmono(float f) {
    u32 u = __float_as_uint(f);
    return (u & 0x80000000u) ? ~u : (u | 0x80000000u);
}

// map flat thread t over all scales -> (s, c, H)
__device__ __forceinline__ void scale_of(int t, int& s, int& c, int& H) {
    if (t < M0)            { s = 0; c = t;           H = 13; }
    else if (t < M0 + M1)  { s = 1; c = t - M0;      H = 26; }
    else                   { s = 2; c = t - M0 - M1; H = 52; }
}

__device__ __forceinline__ float conf_logit(const float* p, int c, int H) {
    int HW = H * H;
    int hw3 = HW * 3;
    int n = c / hw3; int rem = c - n * hw3;
    int pix = rem / 3; int a = rem - pix * 3;
    return p[(size_t)(n * 255 + a * 85) * HW + pix];
}

// ---------------- kernel 1: zero scratch ----------------
__global__ void k_zero(uint8_t* ws) {
    int t = blockIdx.x * blockDim.x + threadIdx.x;
    if (t < 3 * HBINS) ((u32*)(ws + OFF_HIST))[t] = 0;
    if (t < 3 * NSHARD) ((u32*)(ws + OFF_CNT))[t] = 0;
    if (t < NBUCK) ((u32*)(ws + OFF_BCNT))[t] = 0;
    if (t < NBOX) ((u32*)(ws + OFF_KEEP))[t] = 0;
}

// ---------------- kernel 2: per-block LDS histogram + monotone-key cache ----------------
// Same-address atomic storms stay in LDS; global merge is a lane->bin coalesced
// sweep (distinct addresses). Also caches cb[t] so later passes read linearly.
__global__ __launch_bounds__(256) void k_hist(const float* p0, const float* p1, const float* p2,
                                              uint8_t* ws) {
    __shared__ u32 lh[HBINS];
    for (int i = threadIdx.x; i < HBINS; i += 256) lh[i] = 0;
    __syncthreads();
    int b = blockIdx.x, s, b0, nb;
    if (b < 12)      { s = 0; b0 = b;      nb = 12;  }
    else if (b < 60) { s = 1; b0 = b - 12; nb = 48;  }
    else             { s = 2; b0 = b - 60; nb = 196; }
    int M = (s == 0) ? M0 : (s == 1) ? M1 : M2;
    int H = (s == 0) ? 13 : (s == 1) ? 26 : 52;
    int gbase = (s == 0) ? 0 : (s == 1) ? M0 : (M0 + M1);
    const float* p = (s == 0) ? p0 : (s == 1) ? p1 : p2;
    u32* cbp = (u32*)(ws + OFF_CB);
    for (int c = b0 * 256 + threadIdx.x; c < M; c += nb * 256) {
        float conf = sigf(conf_logit(p, c, H));
        u32 cb = fmono(conf);
        cbp[gbase + c] = cb;
        atomicAdd(&lh[cb >> (32 - HBITS)], 1u);
    }
    __syncthreads();
    u32* gh = (u32*)(ws + OFF_HIST) + s * HBINS;
    for (int i = threadIdx.x; i < HBINS; i += 256) {
        u32 v = lh[i];
        if (v) atomicAdd(&gh[i], v);
    }
}

// ---------------- kernel 3: find threshold bin per scale (suffix scan of 8192 bins) ----------------
__global__ __launch_bounds__(1024) void k_scan(uint8_t* ws) {
    int s = blockIdx.x;
    u32* hist = (u32*)(ws + OFF_HIST) + s * HBINS;
    __shared__ u32 sum[1024];
    int t = threadIdx.x;
    u32 acc = 0;
    for (int b = t * 8; b < t * 8 + 8; ++b) acc += hist[b];
    sum[t] = acc;
    __syncthreads();
    for (int off = 1; off < 1024; off <<= 1) {
        u32 v = (t + off < 1024) ? sum[t + off] : 0;
        __syncthreads();
        sum[t] += v;
        __syncthreads();
    }
    u32 excl = (t < 1023) ? sum[t + 1] : 0;       // count in bins above my range
    u32 mine = sum[t] - excl;
    if (excl < K_SEL && excl + mine >= K_SEL) {
        u32 cum = excl; int thr = t * 8;
        for (int b = t * 8 + 7; b >= t * 8; --b) {
            cum += hist[b];
            if (cum >= K_SEL) { thr = b; break; }
        }
        ((u32*)(ws + OFF_THR))[s] = (u32)thr;
    }
}

// ---------------- kernel 4: compact candidates (linear cb read, sharded counters) ----------------
__global__ void k_compact(uint8_t* ws) {
    int t = blockIdx.x * blockDim.x + threadIdx.x;
    if (t >= M_TOT) return;
    int s, c, H; scale_of(t, s, c, H);
    u32 cb = ((u32*)(ws + OFF_CB))[t];
    if ((cb >> (32 - HBITS)) >= ((u32*)(ws + OFF_THR))[s]) {
        int idx = s * NSHARD + (blockIdx.x & (NSHARD - 1));
        u32 pos = atomicAdd(&((u32*)(ws + OFF_CNT))[idx], 1u);
        if (pos < SEG) {
            u64 key = ((u64)cb << 32) | (u32)(~(u32)c);  // ties: smaller c ranks higher
            ((u64*)(ws + OFF_CAND))[(u32)idx * SEG + pos] = key;
        }
    }
}

// ---------------- kernel 5: per-scale gather shards + bitonic sort, emit top-512 ----------------
__global__ __launch_bounds__(1024) void k_sort3(uint8_t* ws) {
    int s = blockIdx.x;
    __shared__ u64 a[CAND_CAP];
    __shared__ u32 scnt[NSHARD], spre[NSHARD];
    __shared__ u32 total_s;
    int t = threadIdx.x;
    if (t < NSHARD) {
        u32 v = ((u32*)(ws + OFF_CNT))[s * NSHARD + t];
        scnt[t] = (v > SEG) ? SEG : v;
        spre[t] = scnt[t];
    }
    __syncthreads();
    for (int off = 1; off < NSHARD; off <<= 1) {          // inclusive Hillis-Steele
        u32 v = (t >= off && t < NSHARD) ? spre[t - off] : 0;
        __syncthreads();
        if (t < NSHARD) spre[t] += v;
        __syncthreads();
    }
    if (t == 0) total_s = (spre[NSHARD - 1] > CAND_CAP) ? CAND_CAP : spre[NSHARD - 1];
    __syncthreads();
    u32 total = total_s;
    int n2 = K_SEL;
    while (n2 < (int)total) n2 <<= 1;
    for (int i = t; i < n2; i += 1024) a[i] = 0ull;
    __syncthreads();
    if (t < NSHARD) {                                      // thread t copies shard t
        u32 base = spre[t] - scnt[t];
        const u64* seg = (const u64*)(ws + OFF_CAND) + ((u32)(s * NSHARD + t)) * SEG;
        for (u32 i = 0; i < scnt[t]; ++i)
            if (base + i < CAND_CAP) a[base + i] = seg[i];
    }
    __syncthreads();
    for (int k = 2; k <= n2; k <<= 1) {
        for (int j = k >> 1; j > 0; j >>= 1) {
            for (int i = t; i < n2; i += 1024) {
                int ixj = i ^ j;
                if (ixj > i) {
                    bool desc = ((i & k) == 0);
                    u64 x = a[i], y = a[ixj];
                    if (desc ? (x < y) : (x > y)) { a[i] = y; a[ixj] = x; }
                }
            }
            __syncthreads();
        }
    }
    u64* topk = (u64*)(ws + OFF_TOPK) + s * K_SEL;
    for (int r = t; r < K_SEL; r += 1024) topk[r] = a[r];
}

// ---------------- kernel 6: decode 1536 boxes + NMS sort keys ----------------
__global__ void k_decode(const float* p0, const float* p1, const float* p2,
                         const float* a0, const float* a1, const float* a2, uint8_t* ws) {
    int t = blockIdx.x * 256 + threadIdx.x;
    if (t >= NBOX) return;
    int s = t / K_SEL;
    int H = (s == 0) ? 13 : (s == 1) ? 26 : 52;
    float stride = (s == 0) ? 32.f : (s == 1) ? 16.f : 8.f;
    const float* p = (s == 0) ? p0 : (s == 1) ? p1 : p2;
    const float* anch = (s == 0) ? a0 : (s == 1) ? a1 : a2;
    int HW = H * H, hw3 = HW * 3;
    u64 key = ((u64*)(ws + OFF_TOPK))[t];
    int c = (int)(~(u32)key);
    int n = c / hw3; int rem = c - n * hw3;
    int pix = rem / 3; int a = rem - pix * 3;
    int h = pix / H, w = pix - h * H;
    size_t base = (size_t)(n * 255 + a * 85) * HW + pix;
    float v0 = p[base];
    float v1 = p[base + HW];
    float v2 = p[base + 2 * (size_t)HW];
    float v3 = p[base + 3 * (size_t)HW];
    float v4 = p[base + 4 * (size_t)HW];
    float conf = sigf(v0);
    float cx = ((float)w + sigf(v1)) * stride;
    float cy = ((float)h + sigf(v2)) * stride;
    float bw = anch[a * 2 + 0] * expf(v3);
    float bh = anch[a * 2 + 1] * expf(v4);
    float best = -INFINITY; int bi = 0;
    for (int k2 = 0; k2 < 80; ++k2) {
        float vv = p[base + (size_t)(5 + k2) * HW];
        if (vv > best) { best = vv; bi = k2; }   // first-occurrence argmax
    }
    float* box = (float*)(ws + OFF_BOX) + t * 7;
    box[0] = (float)n; box[1] = conf; box[2] = cx; box[3] = cy;
    box[4] = bw; box[5] = bh; box[6] = (float)bi;
    bool valid = conf > 0.5f;
    u32 mono = valid ? fmono(conf) : fmono(-INFINITY);
    ((u64*)(ws + OFF_SKEY))[t] = ((u64)mono << 32) | (u32)(~(u32)t);  // ties: smaller pos first
}

// ---------------- kernel 7: sort 1536 by score (stable), build sorted arrays ----------------
__global__ __launch_bounds__(1024) void k_sortnms(uint8_t* ws) {
    __shared__ u64 a[2048];
    int t = threadIdx.x;
    u64* skey = (u64*)(ws + OFF_SKEY);
    for (int i = t; i < 2048; i += 1024) a[i] = (i < NBOX) ? skey[i] : 0ull;
    __syncthreads();
    for (int k = 2; k <= 2048; k <<= 1) {
        for (int j = k >> 1; j > 0; j >>= 1) {
            for (int i = t; i < 2048; i += 1024) {
                int ixj = i ^ j;
                if (ixj > i) {
                    bool desc = ((i & k) == 0);
                    u64 x = a[i], y = a[ixj];
                    if (desc ? (x < y) : (x > y)) { a[i] = y; a[ixj] = x; }
                }
            }
            __syncthreads();
        }
    }
    float* box  = (float*)(ws + OFF_BOX);
    float* sbox = (float*)(ws + OFF_SBOX);
    float* geom = (float*)(ws + OFF_GEOM);
    int*   sbk  = (int*)(ws + OFF_SBK);
    for (int i = t; i < NBOX; i += 1024) {
        int pos = (int)(~(u32)a[i]);
        float b0 = box[pos * 7 + 0], b1 = box[pos * 7 + 1], b2 = box[pos * 7 + 2];
        float b3 = box[pos * 7 + 3], b4 = box[pos * 7 + 4], b5 = box[pos * 7 + 5];
        float b6 = box[pos * 7 + 6];
        sbox[i * 7 + 0] = b0; sbox[i * 7 + 1] = b1; sbox[i * 7 + 2] = b2;
        sbox[i * 7 + 3] = b3; sbox[i * 7 + 4] = b4; sbox[i * 7 + 5] = b5;
        sbox[i * 7 + 6] = b6;
        geom[i]            = b2 - b4 * 0.5f;   // x1
        geom[NBOX + i]     = b3 - b5 * 0.5f;   // y1
        geom[2 * NBOX + i] = b2 + b4 * 0.5f;   // x2
        geom[3 * NBOX + i] = b3 + b5 * 0.5f;   // y2
        geom[4 * NBOX + i] = b4 * b5;          // area
        sbk[i] = (int)b0 * 80 + (int)b6;       // (image, class) bucket id, exact small ints
    }
}

// ---------------- kernel 8: per-box in-bucket rank -> bucket member lists ----------------
__global__ __launch_bounds__(256) void k_rank(uint8_t* ws) {
    __shared__ u16 lbk[NBOX];
    int* sbk = (int*)(ws + OFF_SBK);
    for (int i = threadIdx.x; i < NBOX; i += 256) lbk[i] = (u16)sbk[i];
    __syncthreads();
    int i = blockIdx.x * 256 + threadIdx.x;
    if (i >= NBOX) return;
    u16 b = lbk[i];
    int r = 0;
    for (int j = 0; j < i; ++j) r += (lbk[j] == b) ? 1 : 0;   // no-break, pipelined
    atomicAdd(&((u32*)(ws + OFF_BCNT))[b], 1u);
    if (r < BCAP) ((u16*)(ws + OFF_MEMB))[(u32)b * BCAP + r] = (u16)i;  // unique slot
}

// ---------------- kernel 9: per-bucket serial greedy NMS ----------------
__global__ __launch_bounds__(256) void k_bucket(uint8_t* ws) {
    int b = blockIdx.x * 256 + threadIdx.x;
    if (b >= NBUCK) return;
    u32 cnt = ((u32*)(ws + OFF_BCNT))[b];
    if (cnt == 0) return;
    if (cnt > BCAP) cnt = BCAP;
    const u16* memb = (const u16*)(ws + OFF_MEMB) + (u32)b * BCAP;
    const float* geom = (const float*)(ws + OFF_GEOM);
    const float* sbox = (const float*)(ws + OFF_SBOX);
    u32* keep = (u32*)(ws + OFF_KEEP);
    u32 keptMask = 0;
    for (u32 r = 0; r < cnt; ++r) {
        int i = memb[r];
        float x1 = geom[i], y1 = geom[NBOX + i];
        float x2 = geom[2 * NBOX + i], y2 = geom[3 * NBOX + i];
        float ar = geom[4 * NBOX + i];
        bool val = sbox[i * 7 + 1] > 0.5f;
        bool sup = false;
        for (u32 r2 = 0; r2 < r; ++r2) {
            if (!((keptMask >> r2) & 1u)) continue;   // only active boxes suppress
            int j = memb[r2];
            float ix1 = fmaxf(x1, geom[j]);
            float iy1 = fmaxf(y1, geom[NBOX + j]);
            float ix2 = fminf(x2, geom[2 * NBOX + j]);
            float iy2 = fminf(y2, geom[3 * NBOX + j]);
            float iw = fmaxf(ix2 - ix1, 0.f), ih = fmaxf(iy2 - iy1, 0.f);
            float inter = iw * ih;
            float iou = inter / (ar + geom[4 * NBOX + j] - inter + 1e-9f);
            if (iou > 0.1f) { sup = true; break; }
        }
        bool kept = val && !sup;
        if (kept) keptMask |= (1u << r);
        keep[i] = kept ? 1u : 0u;
    }
}

// ---------------- kernel 10: write outputs ----------------
__global__ void k_out(uint8_t* ws, float* out) {
    int i = blockIdx.x * 256 + threadIdx.x;
    if (i >= NBOX) return;
    float kf = ((u32*)(ws + OFF_KEEP))[i] ? 1.f : 0.f;
    const float* sbox = (const float*)(ws + OFF_SBOX) + i * 7;
    float* o = out + i * 7;
    for (int k2 = 0; k2 < 7; ++k2) o[k2] = sbox[k2] * kf;
    out[NBOX * 7 + i] = kf;
}

extern "C" void kernel_launch(void* const* d_in, const int* in_sizes, int n_in,
                              void* d_out, int out_size, void* d_ws, size_t ws_size,
                              hipStream_t stream) {
    const float* p0 = (const float*)d_in[0];
    const float* p1 = (const float*)d_in[1];
    const float* p2 = (const float*)d_in[2];
    const float* a0 = (const float*)d_in[3];
    const float* a1 = (const float*)d_in[4];
    const float* a2 = (const float*)d_in[5];
    uint8_t* ws = (uint8_t*)d_ws;
    float* out = (float*)d_out;

    const int GB = (M_TOT + 255) / 256;  // 2662

    k_zero   <<<128, 256, 0, stream>>>(ws);
    k_hist   <<<256, 256, 0, stream>>>(p0, p1, p2, ws);
    k_scan   <<<3, 1024, 0, stream>>>(ws);
    k_compact<<<GB, 256, 0, stream>>>(ws);
    k_sort3  <<<3, 1024, 0, stream>>>(ws);
    k_decode <<<6, 256, 0, stream>>>(p0, p1, p2, a0, a1, a2, ws);
    k_sortnms<<<1, 1024, 0, stream>>>(ws);
    k_rank   <<<6, 256, 0, stream>>>(ws);
    k_bucket <<<20, 256, 0, stream>>>(ws);
    k_out    <<<6, 256, 0, stream>>>(ws, out);
}